// Round 4
// baseline (393.636 us; speedup 1.0000x reference)
//
#include <hip/hip_runtime.h>

// Problem: B=8, C=256, H=W=160. n = B*C = 2048 planes.
// Per plane: l[h]=x[h,:]·fcw_w ; alpha=softmax_h(l) ; row[w]=sum_h alpha[h]x[h,w]
//            beta=softmax_w(row*sum(fch_w)) ; s=sum_w beta[w]row[w] ; out[:,:]=s
// Biases are softmax-shift-invariant -> ignored.
//
// R4: flat 3-kernel pipeline (kill the per-plane barrier convoy).
//  A: logits l[n,h] — wave-per-row streaming read of x, shuffle reduce,
//     ZERO barriers, 8 blocks/CU.  (x read #1: HBM, 210 MB)
//  B: softmax + row + beta + s — re-reads x; x (210MB) < L3 (256MB) and was
//     just streamed by A, so read #2 is Infinity-Cache-fed. Inner 160-iter
//     loop is barrier-free; only 4 barriers/plane around tiny reductions.
//  C: broadcast fill of out at fill-rate.
// l and s live in d_ws.

#define HH 160
#define WW 160
#define NPLANE (HH * WW)
#define NPLANES 2048
#define NROWS (NPLANES * HH)   // 327680

// ---------- A: l[r] = x[r,:] . fcw_w ----------
__global__ void __launch_bounds__(256) sa1_logits(
    const float* __restrict__ x,
    const float* __restrict__ fcw_w,
    float* __restrict__ l)
{
    const int wid  = (blockIdx.x * 256 + threadIdx.x) >> 6;  // 8192 waves
    const int lane = threadIdx.x & 63;

    float4 ww = make_float4(0.f, 0.f, 0.f, 0.f);
    if (lane < 40) ww = *(const float4*)(fcw_w + 4 * lane);

#pragma unroll 4
    for (int k = 0; k < 40; ++k) {           // 8192 waves * 40 rows = 327680
        const int r = wid + (k << 13);
        float p = 0.f;
        if (lane < 40) {
            const float4 xv = *(const float4*)(x + (size_t)r * WW + 4 * lane);
            p = xv.x * ww.x + xv.y * ww.y + xv.z * ww.z + xv.w * ww.w;
        }
#pragma unroll
        for (int off = 32; off >= 1; off >>= 1)
            p += __shfl_xor(p, off, 64);
        if (lane == 0) l[r] = p;
    }
}

// ---------- B: per plane, softmax(l) -> row -> beta -> s ----------
__global__ void __launch_bounds__(256) sa1_attn(
    const float* __restrict__ x,
    const float* __restrict__ fch_w,
    const float* __restrict__ l,
    float* __restrict__ s_out)
{
    const int n    = blockIdx.x;
    const int t    = threadIdx.x;
    const int lane = t & 63;
    const int wv   = t >> 6;

    __shared__ float albuf[HH];
    __shared__ float pmax[4], psum[4], pS[4], pzb[4], psd[4];

    // ---- load l[n,:] and fch_w; per-wave partials for max(l) and sum(fch_w) ----
    float lv = -1e30f, fv = 0.f;
    if (t < HH) { lv = l[n * HH + t]; fv = fch_w[t]; }
    float m = lv, fs = fv;
#pragma unroll
    for (int off = 32; off >= 1; off >>= 1) {
        m  = fmaxf(m, __shfl_xor(m, off, 64));
        fs += __shfl_xor(fs, off, 64);
    }
    if (lane == 0) { pmax[wv] = m; pS[wv] = fs; }
    __syncthreads();
    m = fmaxf(fmaxf(pmax[0], pmax[1]), fmaxf(pmax[2], pmax[3]));
    const float S = pS[0] + pS[1] + pS[2] + pS[3];

    // ---- e = exp(l-m); albuf + Z ----
    float e = 0.f;
    if (t < HH) { e = __expf(lv - m); albuf[t] = e; }
    float zs = e;
#pragma unroll
    for (int off = 32; off >= 1; off >>= 1)
        zs += __shfl_xor(zs, off, 64);
    if (lane == 0) psum[wv] = zs;
    __syncthreads();
    const float Z = psum[0] + psum[1] + psum[2] + psum[3];

    // ---- row[w] = sum_h albuf[h] * x[n,h,w]  (w = t, barrier-free, L3-fed) ----
    float acc0 = 0.f, acc1 = 0.f, acc2 = 0.f, acc3 = 0.f;
    if (t < WW) {
        const float* xp = x + (size_t)n * NPLANE + t;
#pragma unroll 4
        for (int h = 0; h < HH; h += 4) {
            acc0 += albuf[h + 0] * xp[(h + 0) * WW];
            acc1 += albuf[h + 1] * xp[(h + 1) * WW];
            acc2 += albuf[h + 2] * xp[(h + 2) * WW];
            acc3 += albuf[h + 3] * xp[(h + 3) * WW];
        }
    }
    const float row = ((acc0 + acc1) + (acc2 + acc3)) / Z;

    // ---- beta softmax + s = sum beta*row ----
    float bl = (t < WW) ? row * S : -1e30f;
    float mb = bl;
#pragma unroll
    for (int off = 32; off >= 1; off >>= 1)
        mb = fmaxf(mb, __shfl_xor(mb, off, 64));
    if (lane == 0) pmax[wv] = mb;   // safe: all pre-loop pmax reads happened
    __syncthreads();                 // before the earlier barrier
    mb = fmaxf(fmaxf(pmax[0], pmax[1]), fmaxf(pmax[2], pmax[3]));

    float e2 = (t < WW) ? __expf(bl - mb) : 0.f;
    float zb = e2, sd = e2 * row;
#pragma unroll
    for (int off = 32; off >= 1; off >>= 1) {
        zb += __shfl_xor(zb, off, 64);
        sd += __shfl_xor(sd, off, 64);
    }
    if (lane == 0) { pzb[wv] = zb; psd[wv] = sd; }
    __syncthreads();
    if (t == 0) {
        const float ZB = pzb[0] + pzb[1] + pzb[2] + pzb[3];
        const float SD = psd[0] + psd[1] + psd[2] + psd[3];
        s_out[n] = SD / ZB;
    }
}

// ---------- C: out[n,:,:] = s[n] ----------
__global__ void __launch_bounds__(256) sa1_bcast(
    const float* __restrict__ s_arr,
    float* __restrict__ out)
{
    const int n = blockIdx.x;
    const int t = threadIdx.x;
    float* op = out + (size_t)n * NPLANE;

    const float sv = s_arr[n];
    const float4 o = make_float4(sv, sv, sv, sv);
#pragma unroll
    for (int k = 0; k < 25; ++k)
        *(float4*)(op + 4 * (size_t)(k * 256 + t)) = o;
}

extern "C" void kernel_launch(void* const* d_in, const int* in_sizes, int n_in,
                              void* d_out, int out_size, void* d_ws, size_t ws_size,
                              hipStream_t stream) {
    const float* x     = (const float*)d_in[0];
    const float* fcw_w = (const float*)d_in[1];
    // d_in[2] = fcw_b: softmax-shift-invariant, unused
    const float* fch_w = (const float*)d_in[3];
    // d_in[4] = fch_b: softmax-shift-invariant, unused
    float* out = (float*)d_out;

    float* l_ws = (float*)d_ws;            // 327680 floats = 1.31 MB
    float* s_ws = l_ws + NROWS;            // 2048 floats

    sa1_logits<<<NPLANES, 256, 0, stream>>>(x, fcw_w, l_ws);
    sa1_attn  <<<NPLANES, 256, 0, stream>>>(x, fch_w, l_ws, s_ws);
    sa1_bcast <<<NPLANES, 256, 0, stream>>>(s_ws, out);
}

// Round 5
// 366.938 us; speedup vs baseline: 1.0728x; 1.0728x over previous
//
#include <hip/hip_runtime.h>

// Problem: B=8, C=256, H=W=160. n = B*C = 2048 planes.
// Per plane: l[h]=x[h,:]·fcw_w ; alpha=softmax_h(l) ; row[w]=sum_h alpha[h]x[h,w]
//            beta=softmax_w(row*sum(fch_w)) ; s=sum_w beta[w]row[w] ; out[:,:]=s
// Biases are softmax-shift-invariant -> ignored.
//
// R5: single-pass ONLINE-softmax reduce (x read exactly once — R4 proved the
// L3 does NOT feed a second pass) + fill-rate broadcast.
// Reduce: 256 thr/block, 4 waves; wave wv streams rows h = wv+4r, r=0..39,
// maintaining running (m, Z, racc[w]) with flash-style rescaling. The row is
// in registers when it is both dotted (l_h) and weighted (racc update), so
// the plane is never held in registers and the streaming loop has ZERO
// barriers. ~32 VGPR, 3 KiB LDS -> __launch_bounds__(256,8): 32 waves/CU,
// 8 resident blocks/CU (vs 2-3 in R1-R3's convoy design).

#define HH 160
#define WW 160
#define NPLANE (HH * WW)
#define NPLANES 2048

__global__ void __launch_bounds__(256, 8) sa1_reduce(
    const float* __restrict__ x,
    const float* __restrict__ fcw_w,
    const float* __restrict__ fch_w,
    float* __restrict__ s_out)
{
    const int n    = blockIdx.x;
    const int t    = threadIdx.x;
    const int lane = t & 63;
    const int wv   = t >> 6;

    __shared__ float racc_s[4 * WW];  // per-wave weighted-row partials
    __shared__ float mzbuf[8];        // per-wave (m, Z)
    __shared__ float pS[4];           // partials of S = sum(fch_w)
    __shared__ float red[12];         // beta-softmax partials

    // ---- S = sum(fch_w): per-wave partial (reduced after the merge barrier) ----
    float fs = (t < HH) ? fch_w[t] : 0.f;
#pragma unroll
    for (int off = 32; off >= 1; off >>= 1) fs += __shfl_xor(fs, off, 64);
    if (lane == 0) pS[wv] = fs;

    float4 ww = make_float4(0.f, 0.f, 0.f, 0.f);
    if (lane < 40) ww = *(const float4*)(fcw_w + 4 * lane);

    const float* xp = x + (size_t)n * NPLANE;

    // ---- stream 40 rows (h = wv + 4r) with online softmax; 1-deep prefetch ----
    float  m = -1e30f, Z = 0.f;
    float4 racc = make_float4(0.f, 0.f, 0.f, 0.f);
    float4 xv_next = make_float4(0.f, 0.f, 0.f, 0.f);
    if (lane < 40) xv_next = *(const float4*)(xp + (size_t)wv * WW + 4 * lane);

    for (int r = 0; r < 40; ++r) {
        const float4 xv = xv_next;
        if (r < 39 && lane < 40)
            xv_next = *(const float4*)(xp + (size_t)(wv + 4 * (r + 1)) * WW + 4 * lane);

        float p = (lane < 40)
                    ? (xv.x * ww.x + xv.y * ww.y + xv.z * ww.z + xv.w * ww.w)
                    : 0.f;
#pragma unroll
        for (int off = 32; off >= 1; off >>= 1) p += __shfl_xor(p, off, 64);
        // p == l_h on every lane
        const float mn = fmaxf(m, p);
        const float c  = __expf(m - mn);   // first iter: exp(-huge) = 0
        const float e  = __expf(p - mn);
        Z = Z * c + e;
        racc.x = racc.x * c + e * xv.x;
        racc.y = racc.y * c + e * xv.y;
        racc.z = racc.z * c + e * xv.z;
        racc.w = racc.w * c + e * xv.w;
        m = mn;
    }

    if (lane < 40) *(float4*)(racc_s + wv * WW + 4 * lane) = racc;
    if (lane == 0) { mzbuf[2 * wv] = m; mzbuf[2 * wv + 1] = Z; }
    __syncthreads();

    // ---- merge 4 online states; row[w] for w = t < 160 ----
    const float S = pS[0] + pS[1] + pS[2] + pS[3];
    const float m0 = mzbuf[0], m1 = mzbuf[2], m2 = mzbuf[4], m3 = mzbuf[6];
    const float M  = fmaxf(fmaxf(m0, m1), fmaxf(m2, m3));
    const float s0 = __expf(m0 - M), s1 = __expf(m1 - M);
    const float s2 = __expf(m2 - M), s3 = __expf(m3 - M);
    const float Zt = s0 * mzbuf[1] + s1 * mzbuf[3] + s2 * mzbuf[5] + s3 * mzbuf[7];

    float row = 0.f;
    if (t < WW) {
        const float rs = s0 * racc_s[0 * WW + t] + s1 * racc_s[1 * WW + t]
                       + s2 * racc_s[2 * WW + t] + s3 * racc_s[3 * WW + t];
        row = rs / Zt;
    }

    // ---- beta softmax + s = sum beta*row ----
    const float bl = (t < WW) ? row * S : -1e30f;
    float mb = bl;
#pragma unroll
    for (int off = 32; off >= 1; off >>= 1) mb = fmaxf(mb, __shfl_xor(mb, off, 64));
    if (lane == 0) red[wv] = mb;
    __syncthreads();
    mb = fmaxf(fmaxf(red[0], red[1]), fmaxf(red[2], red[3]));

    const float e2 = (t < WW) ? __expf(bl - mb) : 0.f;
    float zb = e2, sd = e2 * row;
#pragma unroll
    for (int off = 32; off >= 1; off >>= 1) {
        zb += __shfl_xor(zb, off, 64);
        sd += __shfl_xor(sd, off, 64);
    }
    if (lane == 0) { red[4 + wv] = zb; red[8 + wv] = sd; }
    __syncthreads();
    if (t == 0) {
        const float ZB = red[4] + red[5] + red[6] + red[7];
        const float SD = red[8] + red[9] + red[10] + red[11];
        s_out[n] = SD / ZB;
    }
}

// ---------- broadcast: out[n,:,:] = s[n] at fill rate ----------
__global__ void __launch_bounds__(256) sa1_bcast(
    const float* __restrict__ s_arr,
    float* __restrict__ out)
{
    const int n = blockIdx.x;
    const int t = threadIdx.x;
    float* op = out + (size_t)n * NPLANE;

    const float sv = s_arr[n];
    const float4 o = make_float4(sv, sv, sv, sv);
#pragma unroll
    for (int k = 0; k < 25; ++k)
        *(float4*)(op + 4 * (size_t)(k * 256 + t)) = o;
}

extern "C" void kernel_launch(void* const* d_in, const int* in_sizes, int n_in,
                              void* d_out, int out_size, void* d_ws, size_t ws_size,
                              hipStream_t stream) {
    const float* x     = (const float*)d_in[0];
    const float* fcw_w = (const float*)d_in[1];
    // d_in[2] = fcw_b: softmax-shift-invariant, unused
    const float* fch_w = (const float*)d_in[3];
    // d_in[4] = fch_b: softmax-shift-invariant, unused
    float* out = (float*)d_out;

    float* s_ws = (float*)d_ws;  // 2048 floats

    sa1_reduce<<<NPLANES, 256, 0, stream>>>(x, fcw_w, fch_w, s_ws);
    sa1_bcast <<<NPLANES, 256, 0, stream>>>(s_ws, out);
}

// Round 6
// 365.538 us; speedup vs baseline: 1.0769x; 1.0038x over previous
//
#include <hip/hip_runtime.h>

// Problem: B=8, C=256, H=W=160. n = B*C = 2048 planes.
// Per plane: l[h]=x[h,:]·fcw_w ; alpha=softmax_h(l) ; row[w]=sum_h alpha[h]x[h,w]
//            beta=softmax_w(row*sum(fch_w)) ; s=sum_w beta[w]row[w] ; out[:,:]=s
// Biases are softmax-shift-invariant -> ignored.
//
// R6 = R1 (fused, in-kernel broadcast -> R/W overlap, 1 launch) + R5 (online-
// softmax streaming: no 80-VGPR plane residency, no load-burst/barrier convoy).
// 256 thr/block, 4 waves; wave wv streams rows h = wv+4r (r=0..39) keeping a
// running (m, Z, racc[w]) flash-style state — zero barriers in the stream loop.
// ~50 VGPR, 3 KiB LDS -> launch_bounds(256,8): 8 blocks/CU, so the write phase
// of some blocks overlaps the read phase of others (mixed R/W keeps HBM busy).
// x read exactly once (R4 proved L3 does not feed a second pass).

#define HH 160
#define WW 160
#define NPLANE (HH * WW)
#define NPLANES 2048

__global__ void __launch_bounds__(256, 8) sa1_fused(
    const float* __restrict__ x,
    const float* __restrict__ fcw_w,
    const float* __restrict__ fch_w,
    float* __restrict__ out)
{
    const int n    = blockIdx.x;
    const int t    = threadIdx.x;
    const int lane = t & 63;
    const int wv   = t >> 6;

    __shared__ float racc_s[4 * WW];  // per-wave weighted-row partials
    __shared__ float mzbuf[8];        // per-wave (m, Z)
    __shared__ float pS[4];           // partials of S = sum(fch_w)
    __shared__ float red[12];         // beta-softmax partials
    __shared__ float sval;            // final scalar

    // ---- S = sum(fch_w): per-wave partials (consumed after merge barrier) ----
    float fs = (t < HH) ? fch_w[t] : 0.f;
#pragma unroll
    for (int off = 32; off >= 1; off >>= 1) fs += __shfl_xor(fs, off, 64);
    if (lane == 0) pS[wv] = fs;

    float4 ww = make_float4(0.f, 0.f, 0.f, 0.f);
    if (lane < 40) ww = *(const float4*)(fcw_w + 4 * lane);

    const float* xp = x + (size_t)n * NPLANE;

    // ---- stream 40 rows (h = wv + 4r) with online softmax; 1-deep prefetch ----
    float  m = -1e30f, Z = 0.f;
    float4 racc = make_float4(0.f, 0.f, 0.f, 0.f);
    float4 xv_next = make_float4(0.f, 0.f, 0.f, 0.f);
    if (lane < 40) xv_next = *(const float4*)(xp + (size_t)wv * WW + 4 * lane);

    for (int r = 0; r < 40; ++r) {
        const float4 xv = xv_next;
        if (r < 39 && lane < 40)
            xv_next = *(const float4*)(xp + (size_t)(wv + 4 * (r + 1)) * WW + 4 * lane);

        float p = (lane < 40)
                    ? (xv.x * ww.x + xv.y * ww.y + xv.z * ww.z + xv.w * ww.w)
                    : 0.f;
#pragma unroll
        for (int off = 32; off >= 1; off >>= 1) p += __shfl_xor(p, off, 64);
        // p == l_h on every lane
        const float mn = fmaxf(m, p);
        const float c  = __expf(m - mn);   // first iter: exp(-huge) = 0
        const float e  = __expf(p - mn);
        Z = Z * c + e;
        racc.x = racc.x * c + e * xv.x;
        racc.y = racc.y * c + e * xv.y;
        racc.z = racc.z * c + e * xv.z;
        racc.w = racc.w * c + e * xv.w;
        m = mn;
    }

    if (lane < 40) *(float4*)(racc_s + wv * WW + 4 * lane) = racc;
    if (lane == 0) { mzbuf[2 * wv] = m; mzbuf[2 * wv + 1] = Z; }
    __syncthreads();

    // ---- merge 4 online states; row[w] for w = t < 160 ----
    const float S = pS[0] + pS[1] + pS[2] + pS[3];
    const float m0 = mzbuf[0], m1 = mzbuf[2], m2 = mzbuf[4], m3 = mzbuf[6];
    const float M  = fmaxf(fmaxf(m0, m1), fmaxf(m2, m3));
    const float s0 = __expf(m0 - M), s1 = __expf(m1 - M);
    const float s2 = __expf(m2 - M), s3 = __expf(m3 - M);
    const float Zt = s0 * mzbuf[1] + s1 * mzbuf[3] + s2 * mzbuf[5] + s3 * mzbuf[7];

    float row = 0.f;
    if (t < WW) {
        const float rs = s0 * racc_s[0 * WW + t] + s1 * racc_s[1 * WW + t]
                       + s2 * racc_s[2 * WW + t] + s3 * racc_s[3 * WW + t];
        row = rs / Zt;
    }

    // ---- beta softmax + s = sum beta*row ----
    const float bl = (t < WW) ? row * S : -1e30f;
    float mb = bl;
#pragma unroll
    for (int off = 32; off >= 1; off >>= 1) mb = fmaxf(mb, __shfl_xor(mb, off, 64));
    if (lane == 0) red[wv] = mb;
    __syncthreads();
    mb = fmaxf(fmaxf(red[0], red[1]), fmaxf(red[2], red[3]));

    const float e2 = (t < WW) ? __expf(bl - mb) : 0.f;
    float zb = e2, sd = e2 * row;
#pragma unroll
    for (int off = 32; off >= 1; off >>= 1) {
        zb += __shfl_xor(zb, off, 64);
        sd += __shfl_xor(sd, off, 64);
    }
    if (lane == 0) { red[4 + wv] = zb; red[8 + wv] = sd; }
    __syncthreads();
    if (t == 0) {
        const float ZB = red[4] + red[5] + red[6] + red[7];
        const float SD = red[8] + red[9] + red[10] + red[11];
        sval = SD / ZB;
    }
    __syncthreads();

    // ---- broadcast store (coalesced float4, 25 independent stores) ----
    const float sv = sval;
    float* op = out + (size_t)n * NPLANE;
    const float4 o = make_float4(sv, sv, sv, sv);
#pragma unroll
    for (int k = 0; k < 25; ++k)
        *(float4*)(op + 4 * (size_t)(k * 256 + t)) = o;
}

extern "C" void kernel_launch(void* const* d_in, const int* in_sizes, int n_in,
                              void* d_out, int out_size, void* d_ws, size_t ws_size,
                              hipStream_t stream) {
    const float* x     = (const float*)d_in[0];
    const float* fcw_w = (const float*)d_in[1];
    // d_in[2] = fcw_b: softmax-shift-invariant, unused
    const float* fch_w = (const float*)d_in[3];
    // d_in[4] = fch_b: softmax-shift-invariant, unused
    float* out = (float*)d_out;

    sa1_fused<<<NPLANES, 256, 0, stream>>>(x, fcw_w, fch_w, out);
}